// Round 7
// baseline (220.636 us; speedup 1.0000x reference)
//
#include <hip/hip_runtime.h>

// HierarchicalClassifier: B=16384, D=2048, N_TOP=8, N_CLASS=16
// out[b, t*16+c] = sigmoid(f.top_W[t]+top_b[t]) * softmax_c(f.bottom_W[t,:,c]+bottom_b[t,c])
//
// R7: async global->LDS staging (global_load_lds, width 16) with double-buffered
// K-chunks. R1-R6 all fit "#loads x ~750cyc serialized RTT per wave" -- the
// compiler sinks VGPR-dest loads to their uses. DMA loads have no VGPR dest,
// so all 34 chunk loads stay in flight; one barrier per chunk overlaps chunk
// c+1 transfer with chunk c compute. M=64/block, wave owns 16 rows full-K
// (no reduction); B shared via LDS across waves (L2 B traffic halves).

#define D_DIM 2048
#define NTILE 9          // 144 columns / 16
#define M_ROWS 64        // rows per block, 16 per wave
#define KC 64            // K per staged chunk
#define NCHUNK (D_DIM / KC)   // 32

using f32x4  = float __attribute__((ext_vector_type(4)));
using half8  = _Float16 __attribute__((ext_vector_type(8)));
using fp16x2 = __fp16 __attribute__((ext_vector_type(2)));

typedef const void __attribute__((address_space(1)))* gas_ptr;
typedef void __attribute__((address_space(3)))* lds_ptr;

static __device__ __forceinline__ void dma16(const void* g, void* l) {
    __builtin_amdgcn_global_load_lds((gas_ptr)g, (lds_ptr)l, 16, 0, 0);
}

// Swizzled B layout: S[((kc32*9 + nt)*64 + lane)*8 + j]
//   = W[n = nt*16 + (lane&15)][k = kc32*32 + (lane>>4)*8 + j],  kc32 in [0,64)
// W rows 0..7 = top_W, 8..135 = bottom_W[t][:,c] (n-8 = t*16+c), 136..143 = 0.
__global__ void prep_weights(const float* __restrict__ topW,
                             const float* __restrict__ botW,
                             _Float16* __restrict__ S) {
    int idx = blockIdx.x * blockDim.x + threadIdx.x;   // [0, 64*9*64)
    if (idx >= 64 * NTILE * 64) return;
    int lane = idx & 63;
    int tmp  = idx >> 6;          // kc32*9 + nt
    int nt   = tmp % NTILE;
    int kc   = tmp / NTILE;       // [0,64)
    int n     = nt * 16 + (lane & 15);
    int kbase = kc * 32 + (lane >> 4) * 8;

    _Float16 v[8];
    #pragma unroll
    for (int j = 0; j < 8; j++) {
        int k = kbase + j;
        float x = 0.0f;
        if (n < 8) {
            x = topW[n * D_DIM + k];
        } else if (n < 136) {
            int t = (n - 8) >> 4, c = (n - 8) & 15;
            x = botW[(t * D_DIM + k) * 16 + c];
        }
        v[j] = (_Float16)x;
    }
    *(half8*)(S + (size_t)idx * 8) = *(half8*)v;
}

static __device__ __forceinline__ half8 pack_af(f32x4 a, f32x4 b) {
    fp16x2 p0 = __builtin_amdgcn_cvt_pkrtz(a[0], a[1]);
    fp16x2 p1 = __builtin_amdgcn_cvt_pkrtz(a[2], a[3]);
    fp16x2 p2 = __builtin_amdgcn_cvt_pkrtz(b[0], b[1]);
    fp16x2 p3 = __builtin_amdgcn_cvt_pkrtz(b[2], b[3]);
    half8 r;
    r[0] = (_Float16)p0[0]; r[1] = (_Float16)p0[1];
    r[2] = (_Float16)p1[0]; r[3] = (_Float16)p1[1];
    r[4] = (_Float16)p2[0]; r[5] = (_Float16)p2[1];
    r[6] = (_Float16)p3[0]; r[7] = (_Float16)p3[1];
    return r;
}

__global__ __launch_bounds__(256, 1) void hc_fused(
        const float* __restrict__ feat, const _Float16* __restrict__ Bsw,
        const float* __restrict__ top_b, const float* __restrict__ bot_b,
        float* __restrict__ out) {
    // A chunk: layout [kq][row]: float idx (kq*64 + row)*4 + e ; kq=[0,16), row=[0,64)
    __shared__ float    Abuf[2][4096];          // 16 KB each
    // B chunk: 18 frags of 1KB: half idx f*512 + lane*8 ; f = s*9 + nt, s in {0,1}
    __shared__ _Float16 Bbuf[2][9216];          // 18 KB each
    __shared__ float    red[4][16][148];        // 37.9 KB epilogue exchange

    const int tid  = threadIdx.x;
    const int lane = tid & 63, wave = tid >> 6;
    const int quad = lane >> 4, low = lane & 15;
    const int brow0 = blockIdx.x * M_ROWS;

    // per-lane DMA source bases
    const float*    aSrc = feat + (size_t)(brow0 + lane) * D_DIM;   // lane = row
    const _Float16* bSrc = Bsw + (size_t)lane * 8;

    f32x4 acc[NTILE];
    #pragma unroll
    for (int i = 0; i < NTILE; i++) acc[i] = (f32x4)0.0f;

    // prologue: stage chunk 0 into buf 0
    #pragma unroll
    for (int i = wave; i < 16; i += 4)
        dma16(aSrc + i * 4, &Abuf[0][i * 256]);
    #pragma unroll
    for (int j = wave; j < 18; j += 4)
        dma16(bSrc + j * 512, &Bbuf[0][j * 512]);

    for (int c = 0; c < NCHUNK; c++) {
        __syncthreads();   // drains this wave's DMAs (vmcnt) + joins waves -> buf[c&1] ready
        if (c + 1 < NCHUNK) {
            const int nb = (c + 1) & 1;
            const float*    an = aSrc + (c + 1) * KC;
            const _Float16* bn = bSrc + (size_t)(c + 1) * 18 * 512;
            #pragma unroll
            for (int i = wave; i < 16; i += 4)
                dma16(an + i * 4, &Abuf[nb][i * 256]);
            #pragma unroll
            for (int j = wave; j < 18; j += 4)
                dma16(bn + j * 512, &Bbuf[nb][j * 512]);
        }
        const int cb = c & 1;
        #pragma unroll
        for (int s = 0; s < 2; s++) {
            const int kq = s * 8 + quad * 2;
            f32x4 a0 = *(const f32x4*)&Abuf[cb][(kq * 64 + wave * 16 + low) * 4];
            f32x4 a1 = *(const f32x4*)&Abuf[cb][((kq + 1) * 64 + wave * 16 + low) * 4];
            const half8 af = pack_af(a0, a1);
            #pragma unroll
            for (int nt = 0; nt < NTILE; nt++) {
                half8 bf = *(const half8*)&Bbuf[cb][(s * NTILE + nt) * 512 + lane * 8];
                acc[nt] = __builtin_amdgcn_mfma_f32_16x16x32_f16(af, bf, acc[nt], 0, 0, 0);
            }
        }
    }

    // C/D layout (measured m89/m91): col = lane&15, row-within-wave-tile = quad*4 + reg.
    #pragma unroll
    for (int nt = 0; nt < NTILE; nt++) {
        #pragma unroll
        for (int r = 0; r < 4; r++) {
            red[wave][quad * 4 + r][nt * 16 + low] = acc[nt][r];
        }
    }
    __syncthreads();

    // Epilogue: 64 rows x 8 tops = 512 tasks, 2 per thread.
    #pragma unroll
    for (int rr = 0; rr < 2; rr++) {
        const int row = rr * 32 + (tid >> 3);   // [0,64)
        const int top = tid & 7;
        const int wv = row >> 4, r = row & 15;

        float zt = top_b[top] + red[wv][r][top];
        const float sig = 1.0f / (1.0f + __expf(-zt));

        float z[16];
        float zmax = -1e30f;
        #pragma unroll
        for (int c = 0; c < 16; c++) {
            float v = bot_b[top * 16 + c] + red[wv][r][8 + top * 16 + c];
            z[c] = v;
            zmax = fmaxf(zmax, v);
        }
        float s = 0.0f;
        #pragma unroll
        for (int c = 0; c < 16; c++) { z[c] = __expf(z[c] - zmax); s += z[c]; }
        const float scale = sig / s;

        float* o = out + (size_t)(brow0 + row) * 128 + top * 16;
        #pragma unroll
        for (int c = 0; c < 16; c += 4) {
            f32x4 v = { z[c] * scale, z[c+1] * scale, z[c+2] * scale, z[c+3] * scale };
            *(f32x4*)(o + c) = v;
        }
    }
}

extern "C" void kernel_launch(void* const* d_in, const int* in_sizes, int n_in,
                              void* d_out, int out_size, void* d_ws, size_t ws_size,
                              hipStream_t stream) {
    const float* feat  = (const float*)d_in[0];   // (16384, 2048)
    const float* topW  = (const float*)d_in[1];   // (8, 2048)
    const float* topB  = (const float*)d_in[2];   // (8,)
    const float* botW  = (const float*)d_in[3];   // (8, 2048, 16)
    const float* botB  = (const float*)d_in[4];   // (8, 16)
    float* out = (float*)d_out;                   // (16384, 128)
    _Float16* Bsw = (_Float16*)d_ws;              // 144*2048 fp16 = 576 KB swizzled

    prep_weights<<<(64 * NTILE * 64 + 255) / 256, 256, 0, stream>>>(topW, botW, Bsw);
    hc_fused<<<16384 / M_ROWS, 256, 0, stream>>>(feat, Bsw, topB, botB, out);
}

// Round 8
// 220.613 us; speedup vs baseline: 1.0001x; 1.0001x over previous
//
#include <hip/hip_runtime.h>

// HierarchicalClassifier: B=16384, D=2048, N_TOP=8, N_CLASS=16
// out[b, t*16+c] = sigmoid(f.top_W[t]+top_b[t]) * softmax_c(f.bottom_W[t,:,c]+bottom_b[t,c])
//
// R8: fix R7's A-DMA gather (was 64 scattered 16B slivers/instr = 4x line
// txns). A LDS tile is row-major [row][KC], which is EXACTLY linear in
// lane*16 when instr i loads rows 4i..4i+3 as 4x256B contiguous segments ->
// 16 dense lines/instr (ideal). Also 2 independent 128-thread blocks/CU
// (M=32, grid 512) so one block's barrier drain overlaps the other's compute.

#define D_DIM 2048
#define NTILE 9          // 144 columns / 16
#define M_ROWS 32        // rows per block, 16 per wave (2 waves/block)
#define KC 64            // K floats per staged chunk
#define NCHUNK (D_DIM / KC)   // 32

using f32x4  = float __attribute__((ext_vector_type(4)));
using half8  = _Float16 __attribute__((ext_vector_type(8)));
using fp16x2 = __fp16 __attribute__((ext_vector_type(2)));

typedef const void __attribute__((address_space(1)))* gas_ptr;
typedef void __attribute__((address_space(3)))* lds_ptr;

static __device__ __forceinline__ void dma16(const void* g, void* l) {
    __builtin_amdgcn_global_load_lds((gas_ptr)g, (lds_ptr)l, 16, 0, 0);
}

// Swizzled B layout: S[((kc32*9 + nt)*64 + lane)*8 + j]
//   = W[n = nt*16 + (lane&15)][k = kc32*32 + (lane>>4)*8 + j],  kc32 in [0,64)
// W rows 0..7 = top_W, 8..135 = bottom_W[t][:,c] (n-8 = t*16+c), 136..143 = 0.
__global__ void prep_weights(const float* __restrict__ topW,
                             const float* __restrict__ botW,
                             _Float16* __restrict__ S) {
    int idx = blockIdx.x * blockDim.x + threadIdx.x;   // [0, 64*9*64)
    if (idx >= 64 * NTILE * 64) return;
    int lane = idx & 63;
    int tmp  = idx >> 6;          // kc32*9 + nt
    int nt   = tmp % NTILE;
    int kc   = tmp / NTILE;       // [0,64)
    int n     = nt * 16 + (lane & 15);
    int kbase = kc * 32 + (lane >> 4) * 8;

    _Float16 v[8];
    #pragma unroll
    for (int j = 0; j < 8; j++) {
        int k = kbase + j;
        float x = 0.0f;
        if (n < 8) {
            x = topW[n * D_DIM + k];
        } else if (n < 136) {
            int t = (n - 8) >> 4, c = (n - 8) & 15;
            x = botW[(t * D_DIM + k) * 16 + c];
        }
        v[j] = (_Float16)x;
    }
    *(half8*)(S + (size_t)idx * 8) = *(half8*)v;
}

static __device__ __forceinline__ half8 pack_af(f32x4 a, f32x4 b) {
    fp16x2 p0 = __builtin_amdgcn_cvt_pkrtz(a[0], a[1]);
    fp16x2 p1 = __builtin_amdgcn_cvt_pkrtz(a[2], a[3]);
    fp16x2 p2 = __builtin_amdgcn_cvt_pkrtz(b[0], b[1]);
    fp16x2 p3 = __builtin_amdgcn_cvt_pkrtz(b[2], b[3]);
    half8 r;
    r[0] = (_Float16)p0[0]; r[1] = (_Float16)p0[1];
    r[2] = (_Float16)p1[0]; r[3] = (_Float16)p1[1];
    r[4] = (_Float16)p2[0]; r[5] = (_Float16)p2[1];
    r[6] = (_Float16)p3[0]; r[7] = (_Float16)p3[1];
    return r;
}

__global__ __launch_bounds__(128, 1) void hc_fused(
        const float* __restrict__ feat, const _Float16* __restrict__ Bsw,
        const float* __restrict__ top_b, const float* __restrict__ bot_b,
        float* __restrict__ out) {
    // A chunk: row-major [32][KC] fp32 = 8 KB (exactly linear in DMA lane*16)
    __shared__ float    Abuf[2][M_ROWS * KC];
    // B chunk: 18 frags of 1KB: half idx f*512 + lane*8 ; f = s*9 + nt
    __shared__ _Float16 Bbuf[2][18 * 512];
    __shared__ float    red[M_ROWS][148];          // 18.5 KB epilogue exchange

    const int tid  = threadIdx.x;
    const int lane = tid & 63, wave = tid >> 6;     // 2 waves
    const int quad = lane >> 4, low = lane & 15;
    const int brow0 = blockIdx.x * M_ROWS;

    // A DMA source: instr i covers rows 4i + (lane>>4), bytes (lane&15)*16 of
    // the row's 256B chunk-slice. Dense: 16 cache lines per instr.
    const float* aLane = feat + (size_t)(brow0 + (lane >> 4)) * D_DIM + (lane & 15) * 4;
    const _Float16* bLane = Bsw + lane * 8;

    f32x4 acc[NTILE];
    #pragma unroll
    for (int i = 0; i < NTILE; i++) acc[i] = (f32x4)0.0f;

    // prologue: stage chunk 0 into buf 0 (split DMAs across the 2 waves)
    #pragma unroll
    for (int i = wave; i < 8; i += 2)
        dma16(aLane + i * 4 * D_DIM, &Abuf[0][i * 256 + lane * 4]);
    #pragma unroll
    for (int j = wave; j < 18; j += 2)
        dma16(bLane + j * 512, &Bbuf[0][j * 512 + lane * 8]);

    for (int c = 0; c < NCHUNK; c++) {
        __syncthreads();   // per-wave vmcnt drain + join -> buf[c&1] ready
        if (c + 1 < NCHUNK) {
            const int nb = (c + 1) & 1;
            const float*    an = aLane + (c + 1) * KC;
            const _Float16* bn = bLane + (size_t)(c + 1) * 18 * 512;
            #pragma unroll
            for (int i = wave; i < 8; i += 2)
                dma16(an + i * 4 * D_DIM, &Abuf[nb][i * 256 + lane * 4]);
            #pragma unroll
            for (int j = wave; j < 18; j += 2)
                dma16(bn + j * 512, &Bbuf[nb][j * 512 + lane * 8]);
        }
        const int cb = c & 1;
        #pragma unroll
        for (int s = 0; s < 2; s++) {
            // A frag: rows wave*16+low, k = s*32 + quad*8 .. +8 (fp32, cvt here)
            const float* ar = &Abuf[cb][(wave * 16 + low) * KC + s * 32 + quad * 8];
            f32x4 a0 = *(const f32x4*)(ar);
            f32x4 a1 = *(const f32x4*)(ar + 4);
            const half8 af = pack_af(a0, a1);
            #pragma unroll
            for (int nt = 0; nt < NTILE; nt++) {
                half8 bf = *(const half8*)&Bbuf[cb][(s * NTILE + nt) * 512 + lane * 8];
                acc[nt] = __builtin_amdgcn_mfma_f32_16x16x32_f16(af, bf, acc[nt], 0, 0, 0);
            }
        }
    }

    // C/D layout (measured m89/m91): col = lane&15, row-in-tile = quad*4 + reg.
    #pragma unroll
    for (int nt = 0; nt < NTILE; nt++) {
        #pragma unroll
        for (int r = 0; r < 4; r++) {
            red[wave * 16 + quad * 4 + r][nt * 16 + low] = acc[nt][r];
        }
    }
    __syncthreads();

    // Epilogue: 32 rows x 8 tops = 256 tasks, 2 per thread.
    #pragma unroll
    for (int rr = 0; rr < 2; rr++) {
        const int row = rr * 16 + (tid >> 3);   // [0,32)
        const int top = tid & 7;

        float zt = top_b[top] + red[row][top];
        const float sig = 1.0f / (1.0f + __expf(-zt));

        float z[16];
        float zmax = -1e30f;
        #pragma unroll
        for (int c = 0; c < 16; c++) {
            float v = bot_b[top * 16 + c] + red[row][8 + top * 16 + c];
            z[c] = v;
            zmax = fmaxf(zmax, v);
        }
        float s = 0.0f;
        #pragma unroll
        for (int c = 0; c < 16; c++) { z[c] = __expf(z[c] - zmax); s += z[c]; }
        const float scale = sig / s;

        float* o = out + (size_t)(brow0 + row) * 128 + top * 16;
        #pragma unroll
        for (int c = 0; c < 16; c += 4) {
            f32x4 v = { z[c] * scale, z[c+1] * scale, z[c+2] * scale, z[c+3] * scale };
            *(f32x4*)(o + c) = v;
        }
    }
}

extern "C" void kernel_launch(void* const* d_in, const int* in_sizes, int n_in,
                              void* d_out, int out_size, void* d_ws, size_t ws_size,
                              hipStream_t stream) {
    const float* feat  = (const float*)d_in[0];   // (16384, 2048)
    const float* topW  = (const float*)d_in[1];   // (8, 2048)
    const float* topB  = (const float*)d_in[2];   // (8,)
    const float* botW  = (const float*)d_in[3];   // (8, 2048, 16)
    const float* botB  = (const float*)d_in[4];   // (8, 16)
    float* out = (float*)d_out;                   // (16384, 128)
    _Float16* Bsw = (_Float16*)d_ws;              // 144*2048 fp16 = 576 KB swizzled

    prep_weights<<<(64 * NTILE * 64 + 255) / 256, 256, 0, stream>>>(topW, botW, Bsw);
    hc_fused<<<16384 / M_ROWS, 128, 0, stream>>>(feat, Bsw, topB, botB, out);
}